// Round 1
// baseline (27164.893 us; speedup 1.0000x reference)
//
#include <hip/hip_runtime.h>
#include <hip/hip_bf16.h>
#include <math.h>

// Problem constants
#define BB 8
#define SS 512
#define HH 768
#define NHH 12
#define DHH 64
#define LL 12
#define VV 21128
#define FFF 3072
#define TT (BB*SS)        // 4096 tokens
#define PROMPT 128
#define LN_EPS 1e-12f

// ---------------------------------------------------------------------------
// Generic fp32 GEMM: C[M,N] = A[M,K] @ B[K,N] (+bias) (+gelu)
// A row-major lda=K, B row-major ldb=N, C row-major ldc=N.
// M must be divisible by 64, K by 16. N arbitrary (guarded).
// Block 256 threads, 64x64 tile, BK=16, 4x4 microtile per thread.
// ---------------------------------------------------------------------------
#define BM 64
#define BN 64
#define BK 16

__device__ __forceinline__ float gelu_exact(float x) {
    return 0.5f * x * (1.0f + erff(x * 0.70710678118654752f));
}

__global__ __launch_bounds__(256) void gemm_f32(
    const float* __restrict__ A, const float* __restrict__ Bw,
    const float* __restrict__ bias, float* __restrict__ C,
    int M, int N, int K, int act)
{
    __shared__ float As[BK][BM + 4];
    __shared__ float Bs[BK][BN];

    const int tid = threadIdx.x;
    const int tx = tid & 15;        // 0..15 -> col group
    const int ty = tid >> 4;        // 0..15 -> row group
    const int row0 = blockIdx.y * BM;
    const int col0 = blockIdx.x * BN;

    // load mapping
    const int a_m = tid >> 2;            // 0..63
    const int a_k = (tid & 3) * 4;       // 0,4,8,12
    const int b_k = tid >> 4;            // 0..15
    const int b_n = (tid & 15) * 4;      // 0..60

    float acc[4][4] = {};

    for (int k0 = 0; k0 < K; k0 += BK) {
        // A tile (rows always valid: M % 64 == 0)
        const float4 av = *(const float4*)(A + (size_t)(row0 + a_m) * K + k0 + a_k);
        As[a_k + 0][a_m] = av.x;
        As[a_k + 1][a_m] = av.y;
        As[a_k + 2][a_m] = av.z;
        As[a_k + 3][a_m] = av.w;

        // B tile (guard columns; N % 4 == 0 for all our Ns)
        const int bcol = col0 + b_n;
        float4 bv;
        if (bcol + 3 < N) {
            bv = *(const float4*)(Bw + (size_t)(k0 + b_k) * N + bcol);
        } else {
            bv.x = (bcol + 0 < N) ? Bw[(size_t)(k0 + b_k) * N + bcol + 0] : 0.f;
            bv.y = (bcol + 1 < N) ? Bw[(size_t)(k0 + b_k) * N + bcol + 1] : 0.f;
            bv.z = (bcol + 2 < N) ? Bw[(size_t)(k0 + b_k) * N + bcol + 2] : 0.f;
            bv.w = (bcol + 3 < N) ? Bw[(size_t)(k0 + b_k) * N + bcol + 3] : 0.f;
        }
        *(float4*)&Bs[b_k][b_n] = bv;

        __syncthreads();

        #pragma unroll
        for (int kk = 0; kk < BK; ++kk) {
            const float4 a = *(const float4*)&As[kk][ty * 4];
            const float4 b = *(const float4*)&Bs[kk][tx * 4];
            acc[0][0] += a.x * b.x; acc[0][1] += a.x * b.y; acc[0][2] += a.x * b.z; acc[0][3] += a.x * b.w;
            acc[1][0] += a.y * b.x; acc[1][1] += a.y * b.y; acc[1][2] += a.y * b.z; acc[1][3] += a.y * b.w;
            acc[2][0] += a.z * b.x; acc[2][1] += a.z * b.y; acc[2][2] += a.z * b.z; acc[2][3] += a.z * b.w;
            acc[3][0] += a.w * b.x; acc[3][1] += a.w * b.y; acc[3][2] += a.w * b.z; acc[3][3] += a.w * b.w;
        }
        __syncthreads();
    }

    #pragma unroll
    for (int i = 0; i < 4; ++i) {
        const int row = row0 + ty * 4 + i;
        #pragma unroll
        for (int j = 0; j < 4; ++j) {
            const int col = col0 + tx * 4 + j;
            if (col < N) {
                float v = acc[i][j];
                if (bias) v += bias[col];
                if (act == 1) v = gelu_exact(v);
                C[(size_t)row * N + col] = v;
            }
        }
    }
}

// ---------------------------------------------------------------------------
// Embedding + LayerNorm: h[t] = LN(word_emb[id] + pos_emb[s] + type_emb[0])
// one block per token, 256 threads, H=768 (3 elems/thread)
// ---------------------------------------------------------------------------
__global__ __launch_bounds__(256) void embed_ln(
    const int* __restrict__ ids, const float* __restrict__ we,
    const float* __restrict__ pe, const float* __restrict__ te,
    const float* __restrict__ g, const float* __restrict__ b,
    float* __restrict__ h)
{
    const int t = blockIdx.x;
    const int s = t & (SS - 1);
    const int tid = threadIdx.x;
    __shared__ float x[HH];
    __shared__ float red[256];

    const int id = ids[t];
    for (int j = tid; j < HH; j += 256)
        x[j] = we[(size_t)id * HH + j] + pe[(size_t)s * HH + j] + te[j];
    __syncthreads();

    float sum = x[tid] + x[tid + 256] + x[tid + 512];
    red[tid] = sum; __syncthreads();
    for (int s2 = 128; s2 > 0; s2 >>= 1) { if (tid < s2) red[tid] += red[tid + s2]; __syncthreads(); }
    const float mean = red[0] * (1.0f / HH);
    __syncthreads();

    const float c0 = x[tid] - mean, c1 = x[tid + 256] - mean, c2 = x[tid + 512] - mean;
    red[tid] = c0 * c0 + c1 * c1 + c2 * c2; __syncthreads();
    for (int s2 = 128; s2 > 0; s2 >>= 1) { if (tid < s2) red[tid] += red[tid + s2]; __syncthreads(); }
    const float inv = rsqrtf(red[0] * (1.0f / HH) + LN_EPS);

    h[(size_t)t * HH + tid      ] = c0 * inv * g[tid      ] + b[tid      ];
    h[(size_t)t * HH + tid + 256] = c1 * inv * g[tid + 256] + b[tid + 256];
    h[(size_t)t * HH + tid + 512] = c2 * inv * g[tid + 512] + b[tid + 512];
}

// ---------------------------------------------------------------------------
// Residual add + LayerNorm: hout[t] = LN(resid[t] + y[t]) * g + b
// (bias of the preceding GEMM is already folded into y via GEMM epilogue)
// ---------------------------------------------------------------------------
__global__ __launch_bounds__(256) void add_ln(
    const float* __restrict__ resid, const float* __restrict__ y,
    const float* __restrict__ g, const float* __restrict__ b,
    float* __restrict__ hout)
{
    const int t = blockIdx.x;
    const int tid = threadIdx.x;
    __shared__ float x[HH];
    __shared__ float red[256];

    for (int j = tid; j < HH; j += 256)
        x[j] = resid[(size_t)t * HH + j] + y[(size_t)t * HH + j];
    __syncthreads();

    float sum = x[tid] + x[tid + 256] + x[tid + 512];
    red[tid] = sum; __syncthreads();
    for (int s2 = 128; s2 > 0; s2 >>= 1) { if (tid < s2) red[tid] += red[tid + s2]; __syncthreads(); }
    const float mean = red[0] * (1.0f / HH);
    __syncthreads();

    const float c0 = x[tid] - mean, c1 = x[tid + 256] - mean, c2 = x[tid + 512] - mean;
    red[tid] = c0 * c0 + c1 * c1 + c2 * c2; __syncthreads();
    for (int s2 = 128; s2 > 0; s2 >>= 1) { if (tid < s2) red[tid] += red[tid + s2]; __syncthreads(); }
    const float inv = rsqrtf(red[0] * (1.0f / HH) + LN_EPS);

    hout[(size_t)t * HH + tid      ] = c0 * inv * g[tid      ] + b[tid      ];
    hout[(size_t)t * HH + tid + 256] = c1 * inv * g[tid + 256] + b[tid + 256];
    hout[(size_t)t * HH + tid + 512] = c2 * inv * g[tid + 512] + b[tid + 512];
}

// ---------------------------------------------------------------------------
// Fused attention: one block per (b, head, query i).
// q,k,v: [B*S, NH*DH] row-major. Prefix-LM mask: valid = (j<128) || (j<=i).
// ---------------------------------------------------------------------------
__global__ __launch_bounds__(256) void attn_fused(
    const float* __restrict__ q, const float* __restrict__ k,
    const float* __restrict__ v, float* __restrict__ ctx)
{
    const int i = blockIdx.x;   // query position
    const int hh = blockIdx.y;  // head
    const int b = blockIdx.z;   // batch
    const int tid = threadIdx.x;

    __shared__ float sq[DHH];
    __shared__ float sc[SS];
    __shared__ float red[256];
    __shared__ float part[4][DHH];

    const float* qrow = q + (size_t)(b * SS + i) * HH + hh * DHH;
    if (tid < DHH) sq[tid] = qrow[tid];
    __syncthreads();

    // scores
    for (int j = tid; j < SS; j += 256) {
        const bool valid = (j < PROMPT) || (j <= i);
        float dot = 0.f;
        const float* krow = k + (size_t)(b * SS + j) * HH + hh * DHH;
        #pragma unroll
        for (int d = 0; d < DHH; d += 4) {
            const float4 kv = *(const float4*)(krow + d);
            dot += sq[d] * kv.x + sq[d + 1] * kv.y + sq[d + 2] * kv.z + sq[d + 3] * kv.w;
        }
        sc[j] = valid ? dot * 0.125f : -1e30f;
    }
    __syncthreads();

    // max
    float m = fmaxf(sc[tid], sc[tid + 256]);
    red[tid] = m; __syncthreads();
    for (int s2 = 128; s2 > 0; s2 >>= 1) { if (tid < s2) red[tid] = fmaxf(red[tid], red[tid + s2]); __syncthreads(); }
    const float mx = red[0];
    __syncthreads();

    // exp + sum
    const float e0 = __expf(sc[tid] - mx);
    const float e1 = __expf(sc[tid + 256] - mx);
    sc[tid] = e0; sc[tid + 256] = e1;
    red[tid] = e0 + e1; __syncthreads();
    for (int s2 = 128; s2 > 0; s2 >>= 1) { if (tid < s2) red[tid] += red[tid + s2]; __syncthreads(); }
    const float denom = red[0];
    __syncthreads();

    // P @ V : 64 d-lanes x 4 j-groups
    const int d = tid & 63;
    const int grp = tid >> 6;
    float p = 0.f;
    for (int j = grp * 128; j < (grp + 1) * 128; ++j) {
        p += sc[j] * v[(size_t)(b * SS + j) * HH + hh * DHH + d];
    }
    part[grp][d] = p;
    __syncthreads();

    if (tid < DHH) {
        const float r = (part[0][tid] + part[1][tid] + part[2][tid] + part[3][tid]) / denom;
        ctx[(size_t)(b * SS + i) * HH + hh * DHH + tid] = r;
    }
}

// ---------------------------------------------------------------------------
// CE over one batch-chunk of logits (384 valid rows of batch bidx)
// acc[0] += sum nll, acc[1] += count
// ---------------------------------------------------------------------------
__global__ __launch_bounds__(256) void ce_kernel(
    const float* __restrict__ logits, const int* __restrict__ labels,
    int bidx, float* __restrict__ acc)
{
    const int r = blockIdx.x;                 // 0..383
    const int t = bidx * SS + PROMPT + r;     // global token
    const float* row = logits + (size_t)r * VV;
    const int tid = threadIdx.x;
    __shared__ float red[256];

    float mx = -1e30f;
    for (int c = tid; c < VV; c += 256) mx = fmaxf(mx, row[c]);
    red[tid] = mx; __syncthreads();
    for (int s2 = 128; s2 > 0; s2 >>= 1) { if (tid < s2) red[tid] = fmaxf(red[tid], red[tid + s2]); __syncthreads(); }
    mx = red[0];
    __syncthreads();

    float se = 0.f;
    for (int c = tid; c < VV; c += 256) se += __expf(row[c] - mx);
    red[tid] = se; __syncthreads();
    for (int s2 = 128; s2 > 0; s2 >>= 1) { if (tid < s2) red[tid] += red[tid + s2]; __syncthreads(); }

    if (tid == 0) {
        const int lab = labels[t];
        if (lab >= 0) {
            const float nll = -(row[lab] - mx - logf(red[0]));
            atomicAdd(&acc[0], nll);
            atomicAdd(&acc[1], 1.0f);
        }
    }
}

__global__ void finalize_kernel(const float* __restrict__ acc, float* __restrict__ out)
{
    out[0] = (acc[1] > 0.f) ? acc[0] / acc[1] : 0.f;
}

// ---------------------------------------------------------------------------
extern "C" void kernel_launch(void* const* d_in, const int* in_sizes, int n_in,
                              void* d_out, int out_size, void* d_ws, size_t ws_size,
                              hipStream_t stream)
{
    const int*   input_ids = (const int*)  d_in[0];
    const int*   labels    = (const int*)  d_in[1];
    const float* word_emb  = (const float*)d_in[2];
    const float* pos_emb   = (const float*)d_in[3];
    const float* type_emb  = (const float*)d_in[4];
    const float* emb_ln_g  = (const float*)d_in[5];
    const float* emb_ln_b  = (const float*)d_in[6];
    const float* Wq = (const float*)d_in[7];   const float* bq = (const float*)d_in[8];
    const float* Wk = (const float*)d_in[9];   const float* bk = (const float*)d_in[10];
    const float* Wv = (const float*)d_in[11];  const float* bv = (const float*)d_in[12];
    const float* Wo = (const float*)d_in[13];  const float* bo = (const float*)d_in[14];
    const float* ln1_g = (const float*)d_in[15]; const float* ln1_b = (const float*)d_in[16];
    const float* W1 = (const float*)d_in[17];  const float* bf1 = (const float*)d_in[18];
    const float* W2 = (const float*)d_in[19];  const float* bf2 = (const float*)d_in[20];
    const float* ln2_g = (const float*)d_in[21]; const float* ln2_b = (const float*)d_in[22];
    const float* Wc = (const float*)d_in[23];  const float* bc = (const float*)d_in[24];

    float* ws = (float*)d_ws;
    size_t off = 0;
    float* h    = ws + off; off += (size_t)TT * HH;
    float* qb   = ws + off; off += (size_t)TT * HH;
    float* kb   = ws + off; off += (size_t)TT * HH;
    float* vb   = ws + off; off += (size_t)TT * HH;
    float* ctx  = ws + off; off += (size_t)TT * HH;
    float* tmp  = ws + off; off += (size_t)TT * HH;
    float* ff1  = ws + off; off += (size_t)TT * FFF;
    float* lg   = ws + off; off += (size_t)(SS - PROMPT) * VV;   // 384 x 21128
    float* acc  = ws + off; off += 2;

    hipMemsetAsync(acc, 0, 2 * sizeof(float), stream);

    // embeddings + LN
    embed_ln<<<TT, 256, 0, stream>>>(input_ids, word_emb, pos_emb, type_emb,
                                     emb_ln_g, emb_ln_b, h);

    const dim3 gHH((HH + BN - 1) / BN, TT / BM);   // 12 x 64
    const dim3 gFF((FFF + BN - 1) / BN, TT / BM);  // 48 x 64
    const dim3 gAttn(SS, NHH, BB);

    for (int l = 0; l < LL; ++l) {
        const size_t wo = (size_t)l * HH * HH;
        const size_t w1o = (size_t)l * HH * FFF;
        const size_t w2o = (size_t)l * FFF * HH;

        gemm_f32<<<gHH, 256, 0, stream>>>(h, Wq + wo, bq + (size_t)l * HH, qb, TT, HH, HH, 0);
        gemm_f32<<<gHH, 256, 0, stream>>>(h, Wk + wo, bk + (size_t)l * HH, kb, TT, HH, HH, 0);
        gemm_f32<<<gHH, 256, 0, stream>>>(h, Wv + wo, bv + (size_t)l * HH, vb, TT, HH, HH, 0);

        attn_fused<<<gAttn, 256, 0, stream>>>(qb, kb, vb, ctx);

        gemm_f32<<<gHH, 256, 0, stream>>>(ctx, Wo + wo, bo + (size_t)l * HH, tmp, TT, HH, HH, 0);
        add_ln<<<TT, 256, 0, stream>>>(h, tmp, ln1_g + (size_t)l * HH, ln1_b + (size_t)l * HH, h);

        gemm_f32<<<gFF, 256, 0, stream>>>(h, W1 + w1o, bf1 + (size_t)l * FFF, ff1, TT, FFF, HH, 1);
        gemm_f32<<<gHH, 256, 0, stream>>>(ff1, W2 + w2o, bf2 + (size_t)l * HH, tmp, TT, HH, FFF, 0);
        add_ln<<<TT, 256, 0, stream>>>(h, tmp, ln2_g + (size_t)l * HH, ln2_b + (size_t)l * HH, h);
    }

    // LM head + CE, per batch (only valid rows s >= PROMPT)
    const int Mchunk = SS - PROMPT;  // 384
    const dim3 gV((VV + BN - 1) / BN, Mchunk / BM);  // 331 x 6
    for (int b = 0; b < BB; ++b) {
        const float* Arow = h + (size_t)(b * SS + PROMPT) * HH;
        gemm_f32<<<gV, 256, 0, stream>>>(Arow, Wc, bc, lg, Mchunk, VV, HH, 0);
        ce_kernel<<<Mchunk, 256, 0, stream>>>(lg, labels, b, acc);
    }

    finalize_kernel<<<1, 1, 0, stream>>>(acc, (float*)d_out);
}

// Round 2
// 19042.105 us; speedup vs baseline: 1.4266x; 1.4266x over previous
//
#include <hip/hip_runtime.h>
#include <hip/hip_bf16.h>
#include <math.h>

// Problem constants
#define BB 8
#define SS 512
#define HH 768
#define NHH 12
#define DHH 64
#define LL 12
#define VV 21128
#define FFF 3072
#define TT (BB*SS)        // 4096 tokens
#define PROMPT 128
#define LN_EPS 1e-12f

// ---------------------------------------------------------------------------
// Generic fp32 GEMM: C[M,N] = A[M,K] @ B[K,N] (+bias) (+gelu)
// ---------------------------------------------------------------------------
#define BM 64
#define BN 64
#define BK 16

__device__ __forceinline__ float gelu_exact(float x) {
    return 0.5f * x * (1.0f + erff(x * 0.70710678118654752f));
}

__global__ __launch_bounds__(256) void gemm_f32(
    const float* __restrict__ A, const float* __restrict__ Bw,
    const float* __restrict__ bias, float* __restrict__ C,
    int M, int N, int K, int act)
{
    __shared__ float As[BK][BM + 4];
    __shared__ float Bs[BK][BN];

    const int tid = threadIdx.x;
    const int tx = tid & 15;
    const int ty = tid >> 4;
    const int row0 = blockIdx.y * BM;
    const int col0 = blockIdx.x * BN;

    const int a_m = tid >> 2;
    const int a_k = (tid & 3) * 4;
    const int b_k = tid >> 4;
    const int b_n = (tid & 15) * 4;

    float acc[4][4] = {};

    for (int k0 = 0; k0 < K; k0 += BK) {
        const float4 av = *(const float4*)(A + (size_t)(row0 + a_m) * K + k0 + a_k);
        As[a_k + 0][a_m] = av.x;
        As[a_k + 1][a_m] = av.y;
        As[a_k + 2][a_m] = av.z;
        As[a_k + 3][a_m] = av.w;

        const int bcol = col0 + b_n;
        float4 bv;
        if (bcol + 3 < N) {
            bv = *(const float4*)(Bw + (size_t)(k0 + b_k) * N + bcol);
        } else {
            bv.x = (bcol + 0 < N) ? Bw[(size_t)(k0 + b_k) * N + bcol + 0] : 0.f;
            bv.y = (bcol + 1 < N) ? Bw[(size_t)(k0 + b_k) * N + bcol + 1] : 0.f;
            bv.z = (bcol + 2 < N) ? Bw[(size_t)(k0 + b_k) * N + bcol + 2] : 0.f;
            bv.w = (bcol + 3 < N) ? Bw[(size_t)(k0 + b_k) * N + bcol + 3] : 0.f;
        }
        *(float4*)&Bs[b_k][b_n] = bv;

        __syncthreads();

        #pragma unroll
        for (int kk = 0; kk < BK; ++kk) {
            const float4 a = *(const float4*)&As[kk][ty * 4];
            const float4 b = *(const float4*)&Bs[kk][tx * 4];
            acc[0][0] += a.x * b.x; acc[0][1] += a.x * b.y; acc[0][2] += a.x * b.z; acc[0][3] += a.x * b.w;
            acc[1][0] += a.y * b.x; acc[1][1] += a.y * b.y; acc[1][2] += a.y * b.z; acc[1][3] += a.y * b.w;
            acc[2][0] += a.z * b.x; acc[2][1] += a.z * b.y; acc[2][2] += a.z * b.z; acc[2][3] += a.z * b.w;
            acc[3][0] += a.w * b.x; acc[3][1] += a.w * b.y; acc[3][2] += a.w * b.z; acc[3][3] += a.w * b.w;
        }
        __syncthreads();
    }

    #pragma unroll
    for (int i = 0; i < 4; ++i) {
        const int row = row0 + ty * 4 + i;
        #pragma unroll
        for (int j = 0; j < 4; ++j) {
            const int col = col0 + tx * 4 + j;
            if (col < N) {
                float v = acc[i][j];
                if (bias) v += bias[col];
                if (act == 1) v = gelu_exact(v);
                C[(size_t)row * N + col] = v;
            }
        }
    }
}

// ---------------------------------------------------------------------------
// Embedding + LayerNorm
// ---------------------------------------------------------------------------
__global__ __launch_bounds__(256) void embed_ln(
    const int* __restrict__ ids, const float* __restrict__ we,
    const float* __restrict__ pe, const float* __restrict__ te,
    const float* __restrict__ g, const float* __restrict__ b,
    float* __restrict__ h)
{
    const int t = blockIdx.x;
    const int s = t & (SS - 1);
    const int tid = threadIdx.x;
    __shared__ float x[HH];
    __shared__ float red[256];

    const int id = ids[t];
    for (int j = tid; j < HH; j += 256)
        x[j] = we[(size_t)id * HH + j] + pe[(size_t)s * HH + j] + te[j];
    __syncthreads();

    float sum = x[tid] + x[tid + 256] + x[tid + 512];
    red[tid] = sum; __syncthreads();
    for (int s2 = 128; s2 > 0; s2 >>= 1) { if (tid < s2) red[tid] += red[tid + s2]; __syncthreads(); }
    const float mean = red[0] * (1.0f / HH);
    __syncthreads();

    const float c0 = x[tid] - mean, c1 = x[tid + 256] - mean, c2 = x[tid + 512] - mean;
    red[tid] = c0 * c0 + c1 * c1 + c2 * c2; __syncthreads();
    for (int s2 = 128; s2 > 0; s2 >>= 1) { if (tid < s2) red[tid] += red[tid + s2]; __syncthreads(); }
    const float inv = rsqrtf(red[0] * (1.0f / HH) + LN_EPS);

    h[(size_t)t * HH + tid      ] = c0 * inv * g[tid      ] + b[tid      ];
    h[(size_t)t * HH + tid + 256] = c1 * inv * g[tid + 256] + b[tid + 256];
    h[(size_t)t * HH + tid + 512] = c2 * inv * g[tid + 512] + b[tid + 512];
}

// ---------------------------------------------------------------------------
// Residual add + LayerNorm
// ---------------------------------------------------------------------------
__global__ __launch_bounds__(256) void add_ln(
    const float* __restrict__ resid, const float* __restrict__ y,
    const float* __restrict__ g, const float* __restrict__ b,
    float* __restrict__ hout)
{
    const int t = blockIdx.x;
    const int tid = threadIdx.x;
    __shared__ float x[HH];
    __shared__ float red[256];

    for (int j = tid; j < HH; j += 256)
        x[j] = resid[(size_t)t * HH + j] + y[(size_t)t * HH + j];
    __syncthreads();

    float sum = x[tid] + x[tid + 256] + x[tid + 512];
    red[tid] = sum; __syncthreads();
    for (int s2 = 128; s2 > 0; s2 >>= 1) { if (tid < s2) red[tid] += red[tid + s2]; __syncthreads(); }
    const float mean = red[0] * (1.0f / HH);
    __syncthreads();

    const float c0 = x[tid] - mean, c1 = x[tid + 256] - mean, c2 = x[tid + 512] - mean;
    red[tid] = c0 * c0 + c1 * c1 + c2 * c2; __syncthreads();
    for (int s2 = 128; s2 > 0; s2 >>= 1) { if (tid < s2) red[tid] += red[tid + s2]; __syncthreads(); }
    const float inv = rsqrtf(red[0] * (1.0f / HH) + LN_EPS);

    hout[(size_t)t * HH + tid      ] = c0 * inv * g[tid      ] + b[tid      ];
    hout[(size_t)t * HH + tid + 256] = c1 * inv * g[tid + 256] + b[tid + 256];
    hout[(size_t)t * HH + tid + 512] = c2 * inv * g[tid + 512] + b[tid + 512];
}

// ---------------------------------------------------------------------------
// Flash-style attention: one WAVE (64 threads) per block; block owns 64
// queries of one (b, head). Thread = one query. K/V staged in LDS in 64-key
// tiles; online softmax with (m, l, O[64]) in registers.
// Prefix-LM mask: valid(j) = j < 128 || j <= i. For a query tile
// [qb, qb+64), only keys j < max(qb+64, 128) are ever valid, and that bound
// is always a multiple of 64 -> full tiles only, 53% of S^2 work skipped.
// ---------------------------------------------------------------------------
#define QT 64

__global__ __launch_bounds__(64) void attn_flash(
    const float* __restrict__ q, const float* __restrict__ k,
    const float* __restrict__ v, float* __restrict__ ctx)
{
    const int qb   = blockIdx.x * QT;
    const int hh   = blockIdx.y;
    const int b    = blockIdx.z;
    const int lane = threadIdx.x;       // 0..63
    const int i    = qb + lane;         // this thread's query index

    __shared__ float Ks[64][DHH];       // 16 KB
    __shared__ float Vs[64][DHH];       // 16 KB

    // Q row -> registers
    float qreg[DHH];
    {
        const float* qrow = q + (size_t)(b * SS + i) * HH + hh * DHH;
        #pragma unroll
        for (int d = 0; d < DHH; d += 4) {
            const float4 t4 = *(const float4*)(qrow + d);
            qreg[d] = t4.x; qreg[d + 1] = t4.y; qreg[d + 2] = t4.z; qreg[d + 3] = t4.w;
        }
    }

    float o[DHH];
    #pragma unroll
    for (int d = 0; d < DHH; ++d) o[d] = 0.f;
    float m = -1e30f, lsum = 0.f;

    const int maxi = qb + QT - 1;
    const int kmax = (maxi < PROMPT) ? PROMPT : (maxi + 1);   // multiple of 64

    const int ldr = lane >> 4;            // 0..3 row offset within group of 4
    const int ldc = (lane & 15) * 4;      // 0..60 col

    for (int j0 = 0; j0 < kmax; j0 += 64) {
        // stage K/V tile: 4 rows per iteration, 16 lanes per row (float4)
        #pragma unroll
        for (int r4 = 0; r4 < 64; r4 += 4) {
            const int r = r4 + ldr;
            const size_t rowoff = (size_t)(b * SS + j0 + r) * HH + hh * DHH + ldc;
            *(float4*)&Ks[r][ldc] = *(const float4*)(k + rowoff);
            *(float4*)&Vs[r][ldc] = *(const float4*)(v + rowoff);
        }
        __syncthreads();

        const bool tile_all_valid = (j0 + 63 < PROMPT) || (j0 + 63 <= i);

        for (int jj = 0; jj < 64; ++jj) {
            const int j = j0 + jj;
            float dot = 0.f;
            #pragma unroll
            for (int d = 0; d < DHH; d += 4) {
                const float4 k4 = *(const float4*)&Ks[jj][d];
                dot += qreg[d] * k4.x + qreg[d + 1] * k4.y
                     + qreg[d + 2] * k4.z + qreg[d + 3] * k4.w;
            }
            float s = dot * 0.125f;
            if (!tile_all_valid) {
                const bool valid = (j < PROMPT) || (j <= i);
                s = valid ? s : -1e30f;
            }
            const float mnew = fmaxf(m, s);
            const float corr = __expf(m - mnew);
            const float p    = __expf(s - mnew);
            lsum = lsum * corr + p;
            #pragma unroll
            for (int d = 0; d < DHH; d += 4) {
                const float4 v4 = *(const float4*)&Vs[jj][d];
                o[d]     = o[d]     * corr + p * v4.x;
                o[d + 1] = o[d + 1] * corr + p * v4.y;
                o[d + 2] = o[d + 2] * corr + p * v4.z;
                o[d + 3] = o[d + 3] * corr + p * v4.w;
            }
            m = mnew;
        }
        __syncthreads();
    }

    // write out
    const float inv = 1.0f / lsum;
    float* crow = ctx + (size_t)(b * SS + i) * HH + hh * DHH;
    #pragma unroll
    for (int d = 0; d < DHH; d += 4) {
        float4 t4;
        t4.x = o[d] * inv; t4.y = o[d + 1] * inv;
        t4.z = o[d + 2] * inv; t4.w = o[d + 3] * inv;
        *(float4*)(crow + d) = t4;
    }
}

// ---------------------------------------------------------------------------
// CE over one batch-chunk of logits
// ---------------------------------------------------------------------------
__global__ __launch_bounds__(256) void ce_kernel(
    const float* __restrict__ logits, const int* __restrict__ labels,
    int bidx, float* __restrict__ acc)
{
    const int r = blockIdx.x;
    const int t = bidx * SS + PROMPT + r;
    const float* row = logits + (size_t)r * VV;
    const int tid = threadIdx.x;
    __shared__ float red[256];

    float mx = -1e30f;
    for (int c = tid; c < VV; c += 256) mx = fmaxf(mx, row[c]);
    red[tid] = mx; __syncthreads();
    for (int s2 = 128; s2 > 0; s2 >>= 1) { if (tid < s2) red[tid] = fmaxf(red[tid], red[tid + s2]); __syncthreads(); }
    mx = red[0];
    __syncthreads();

    float se = 0.f;
    for (int c = tid; c < VV; c += 256) se += __expf(row[c] - mx);
    red[tid] = se; __syncthreads();
    for (int s2 = 128; s2 > 0; s2 >>= 1) { if (tid < s2) red[tid] += red[tid + s2]; __syncthreads(); }

    if (tid == 0) {
        const int lab = labels[t];
        if (lab >= 0) {
            const float nll = -(row[lab] - mx - logf(red[0]));
            atomicAdd(&acc[0], nll);
            atomicAdd(&acc[1], 1.0f);
        }
    }
}

__global__ void finalize_kernel(const float* __restrict__ acc, float* __restrict__ out)
{
    out[0] = (acc[1] > 0.f) ? acc[0] / acc[1] : 0.f;
}

// ---------------------------------------------------------------------------
extern "C" void kernel_launch(void* const* d_in, const int* in_sizes, int n_in,
                              void* d_out, int out_size, void* d_ws, size_t ws_size,
                              hipStream_t stream)
{
    const int*   input_ids = (const int*)  d_in[0];
    const int*   labels    = (const int*)  d_in[1];
    const float* word_emb  = (const float*)d_in[2];
    const float* pos_emb   = (const float*)d_in[3];
    const float* type_emb  = (const float*)d_in[4];
    const float* emb_ln_g  = (const float*)d_in[5];
    const float* emb_ln_b  = (const float*)d_in[6];
    const float* Wq = (const float*)d_in[7];   const float* bq = (const float*)d_in[8];
    const float* Wk = (const float*)d_in[9];   const float* bk = (const float*)d_in[10];
    const float* Wv = (const float*)d_in[11];  const float* bv = (const float*)d_in[12];
    const float* Wo = (const float*)d_in[13];  const float* bo = (const float*)d_in[14];
    const float* ln1_g = (const float*)d_in[15]; const float* ln1_b = (const float*)d_in[16];
    const float* W1 = (const float*)d_in[17];  const float* bf1 = (const float*)d_in[18];
    const float* W2 = (const float*)d_in[19];  const float* bf2 = (const float*)d_in[20];
    const float* ln2_g = (const float*)d_in[21]; const float* ln2_b = (const float*)d_in[22];
    const float* Wc = (const float*)d_in[23];  const float* bc = (const float*)d_in[24];

    float* ws = (float*)d_ws;
    size_t off = 0;
    float* h    = ws + off; off += (size_t)TT * HH;
    float* qb2  = ws + off; off += (size_t)TT * HH;
    float* kb2  = ws + off; off += (size_t)TT * HH;
    float* vb2  = ws + off; off += (size_t)TT * HH;
    float* ctx  = ws + off; off += (size_t)TT * HH;
    float* tmp  = ws + off; off += (size_t)TT * HH;
    float* ff1  = ws + off; off += (size_t)TT * FFF;
    float* lg   = ws + off; off += (size_t)(SS - PROMPT) * VV;
    float* acc  = ws + off; off += 2;

    hipMemsetAsync(acc, 0, 2 * sizeof(float), stream);

    embed_ln<<<TT, 256, 0, stream>>>(input_ids, word_emb, pos_emb, type_emb,
                                     emb_ln_g, emb_ln_b, h);

    const dim3 gHH((HH + BN - 1) / BN, TT / BM);   // 12 x 64
    const dim3 gFF((FFF + BN - 1) / BN, TT / BM);  // 48 x 64
    const dim3 gAttn(SS / QT, NHH, BB);            // 8 x 12 x 8 = 768 blocks

    for (int l = 0; l < LL; ++l) {
        const size_t wo = (size_t)l * HH * HH;
        const size_t w1o = (size_t)l * HH * FFF;
        const size_t w2o = (size_t)l * FFF * HH;

        gemm_f32<<<gHH, 256, 0, stream>>>(h, Wq + wo, bq + (size_t)l * HH, qb2, TT, HH, HH, 0);
        gemm_f32<<<gHH, 256, 0, stream>>>(h, Wk + wo, bk + (size_t)l * HH, kb2, TT, HH, HH, 0);
        gemm_f32<<<gHH, 256, 0, stream>>>(h, Wv + wo, bv + (size_t)l * HH, vb2, TT, HH, HH, 0);

        attn_flash<<<gAttn, 64, 0, stream>>>(qb2, kb2, vb2, ctx);

        gemm_f32<<<gHH, 256, 0, stream>>>(ctx, Wo + wo, bo + (size_t)l * HH, tmp, TT, HH, HH, 0);
        add_ln<<<TT, 256, 0, stream>>>(h, tmp, ln1_g + (size_t)l * HH, ln1_b + (size_t)l * HH, h);

        gemm_f32<<<gFF, 256, 0, stream>>>(h, W1 + w1o, bf1 + (size_t)l * FFF, ff1, TT, FFF, HH, 1);
        gemm_f32<<<gHH, 256, 0, stream>>>(ff1, W2 + w2o, bf2 + (size_t)l * HH, tmp, TT, HH, FFF, 0);
        add_ln<<<TT, 256, 0, stream>>>(h, tmp, ln2_g + (size_t)l * HH, ln2_b + (size_t)l * HH, h);
    }

    const int Mchunk = SS - PROMPT;  // 384
    const dim3 gV((VV + BN - 1) / BN, Mchunk / BM);
    for (int b = 0; b < BB; ++b) {
        const float* Arow = h + (size_t)(b * SS + PROMPT) * HH;
        gemm_f32<<<gV, 256, 0, stream>>>(Arow, Wc, bc, lg, Mchunk, VV, HH, 0);
        ce_kernel<<<Mchunk, 256, 0, stream>>>(lg, labels, b, acc);
    }

    finalize_kernel<<<1, 1, 0, stream>>>(acc, (float*)d_out);
}

// Round 3
// 8071.084 us; speedup vs baseline: 3.3657x; 2.3593x over previous
//
#include <hip/hip_runtime.h>
#include <hip/hip_bf16.h>
#include <math.h>

// Problem constants
#define BB 8
#define SS 512
#define HH 768
#define NHH 12
#define DHH 64
#define LL 12
#define VV 21128
#define VVP 21248          // VV padded up to multiple of 128
#define FFF 3072
#define TT (BB*SS)         // 4096 tokens
#define PROMPT 128
#define LN_EPS 1e-12f
#define QKVN (3*HH)        // 2304

typedef __attribute__((ext_vector_type(8))) short short8;
typedef __attribute__((ext_vector_type(4))) float floatx4;

__device__ __forceinline__ float gelu_exact(float x) {
    return 0.5f * x * (1.0f + erff(x * 0.70710678118654752f));
}

// async global->LDS, 16B per lane; ldsptr must be wave-uniform
__device__ __forceinline__ void load16_lds(const void* gptr, void* ldsptr) {
    __builtin_amdgcn_global_load_lds(
        (const __attribute__((address_space(1))) unsigned int*)(unsigned long long)(gptr),
        (__attribute__((address_space(3))) unsigned int*)(unsigned long long)(ldsptr),
        16, 0, 0);
}

// ---------------------------------------------------------------------------
// bf16 MFMA GEMM: C[M,N] = A[M,K] @ Bt[N,K]^T (+bias) (+gelu)
// A row-major [M,K] bf16 (K-contig), Bt row-major [Npad,K] bf16 (K-contig).
// 128x128 tile, BK=32, 256 threads = 4 waves (2x2 of 64x64), 4x4 MFMA frags.
// M % 128 == 0. N ragged allowed (epilogue guard; Bt rows padded to 128).
// ---------------------------------------------------------------------------
__global__ __launch_bounds__(256) void gemm_mfma(
    const __hip_bfloat16* __restrict__ A,
    const __hip_bfloat16* __restrict__ Bt,
    const float* __restrict__ bias,
    float* __restrict__ Cf,            // fp32 out (or null)
    __hip_bfloat16* __restrict__ Ch,   // bf16 out (or null)
    int M, int N, int K, int act)
{
    __shared__ __hip_bfloat16 As[128 * 32];   // 8 KB
    __shared__ __hip_bfloat16 Bs[128 * 32];   // 8 KB

    const int tid  = threadIdx.x;
    const int warp = tid >> 6;
    const int row0 = blockIdx.y * 128;
    const int col0 = blockIdx.x * 128;

    const int wm = warp >> 1, wn = warp & 1;
    const int lane = tid & 63;
    const int lr = lane >> 4, lc = lane & 15;

    floatx4 acc[4][4] = {};

    // staging map: seg = tid + p*256; row = seg/4; col8 = (seg%4)*8
    const int sRow = tid >> 2;
    const int sCol = (tid & 3) << 3;
    const __hip_bfloat16* aG0 = A  + (size_t)(row0 + sRow)      * K + sCol;
    const __hip_bfloat16* aG1 = A  + (size_t)(row0 + sRow + 64) * K + sCol;
    const __hip_bfloat16* bG0 = Bt + (size_t)(col0 + sRow)      * K + sCol;
    const __hip_bfloat16* bG1 = Bt + (size_t)(col0 + sRow + 64) * K + sCol;

    char* aL = (char*)As + warp * 1024;
    char* bL = (char*)Bs + warp * 1024;

    for (int k0 = 0; k0 < K; k0 += 32) {
        load16_lds(aG0 + k0, aL);
        load16_lds(aG1 + k0, aL + 4096);
        load16_lds(bG0 + k0, bL);
        load16_lds(bG1 + k0, bL + 4096);
        __syncthreads();

        short8 af[4], bf[4];
        #pragma unroll
        for (int mt = 0; mt < 4; ++mt)
            af[mt] = *(const short8*)((const char*)As + (((wm * 64 + mt * 16 + lc) * 32) + lr * 8) * 2);
        #pragma unroll
        for (int nt = 0; nt < 4; ++nt)
            bf[nt] = *(const short8*)((const char*)Bs + (((wn * 64 + nt * 16 + lc) * 32) + lr * 8) * 2);

        #pragma unroll
        for (int mt = 0; mt < 4; ++mt)
            #pragma unroll
            for (int nt = 0; nt < 4; ++nt)
                acc[mt][nt] = __builtin_amdgcn_mfma_f32_16x16x32_bf16(
                    af[mt], bf[nt], acc[mt][nt], 0, 0, 0);
        __syncthreads();
    }

    #pragma unroll
    for (int mt = 0; mt < 4; ++mt) {
        #pragma unroll
        for (int nt = 0; nt < 4; ++nt) {
            const int n = col0 + wn * 64 + nt * 16 + lc;
            if (n < N) {
                #pragma unroll
                for (int r = 0; r < 4; ++r) {
                    const int m = row0 + wm * 64 + mt * 16 + lr * 4 + r;
                    float v = acc[mt][nt][r];
                    if (bias) v += bias[n];
                    if (act)  v = gelu_exact(v);
                    if (Cf) Cf[(size_t)m * N + n] = v;
                    if (Ch) Ch[(size_t)m * N + n] = __float2bfloat16(v);
                }
            }
        }
    }
}

// ---------------------------------------------------------------------------
// fp32 -> bf16 transpose: out[z][row_off + n][k] = (bf16) W[z][k][n]
// ---------------------------------------------------------------------------
__global__ void transpose_cvt(
    const float* __restrict__ W, __hip_bfloat16* __restrict__ out,
    int K, int N, long long in_lstride, long long out_lstride,
    int row_off, int out_ld)
{
    __shared__ float t[32][33];
    const int n0 = blockIdx.x * 32;
    const int k0 = blockIdx.y * 32;
    const int z  = blockIdx.z;
    const int tx = threadIdx.x, ty = threadIdx.y;

    const float* Wz = W + (size_t)z * in_lstride;
    __hip_bfloat16* Oz = out + (size_t)z * out_lstride;

    #pragma unroll
    for (int r = 0; r < 4; ++r) {
        const int k = k0 + ty + r * 8;
        const int n = n0 + tx;
        if (k < K && n < N) t[ty + r * 8][tx] = Wz[(size_t)k * N + n];
    }
    __syncthreads();
    #pragma unroll
    for (int r = 0; r < 4; ++r) {
        const int n = n0 + ty + r * 8;
        const int k = k0 + tx;
        if (n < N && k < K)
            Oz[(size_t)(row_off + n) * out_ld + k] = __float2bfloat16(t[tx][ty + r * 8]);
    }
}

__global__ void concat_bias(const float* __restrict__ bq, const float* __restrict__ bk,
                            const float* __restrict__ bv, float* __restrict__ bqkv)
{
    const int i = blockIdx.x * 256 + threadIdx.x;
    if (i >= LL * QKVN) return;
    const int l = i / QKVN, j = i % QKVN;
    float v;
    if (j < HH)            v = bq[l * HH + j];
    else if (j < 2 * HH)   v = bk[l * HH + j - HH];
    else                   v = bv[l * HH + j - 2 * HH];
    bqkv[i] = v;
}

// ---------------------------------------------------------------------------
// Embedding + LayerNorm -> bf16 h
// ---------------------------------------------------------------------------
__global__ __launch_bounds__(256) void embed_ln(
    const int* __restrict__ ids, const float* __restrict__ we,
    const float* __restrict__ pe, const float* __restrict__ te,
    const float* __restrict__ g, const float* __restrict__ b,
    __hip_bfloat16* __restrict__ h)
{
    const int t = blockIdx.x;
    const int s = t & (SS - 1);
    const int tid = threadIdx.x;
    __shared__ float x[HH];
    __shared__ float red[256];

    const int id = ids[t];
    for (int j = tid; j < HH; j += 256)
        x[j] = we[(size_t)id * HH + j] + pe[(size_t)s * HH + j] + te[j];
    __syncthreads();

    float sum = x[tid] + x[tid + 256] + x[tid + 512];
    red[tid] = sum; __syncthreads();
    for (int s2 = 128; s2 > 0; s2 >>= 1) { if (tid < s2) red[tid] += red[tid + s2]; __syncthreads(); }
    const float mean = red[0] * (1.0f / HH);
    __syncthreads();

    const float c0 = x[tid] - mean, c1 = x[tid + 256] - mean, c2 = x[tid + 512] - mean;
    red[tid] = c0 * c0 + c1 * c1 + c2 * c2; __syncthreads();
    for (int s2 = 128; s2 > 0; s2 >>= 1) { if (tid < s2) red[tid] += red[tid + s2]; __syncthreads(); }
    const float inv = rsqrtf(red[0] * (1.0f / HH) + LN_EPS);

    h[(size_t)t * HH + tid      ] = __float2bfloat16(c0 * inv * g[tid      ] + b[tid      ]);
    h[(size_t)t * HH + tid + 256] = __float2bfloat16(c1 * inv * g[tid + 256] + b[tid + 256]);
    h[(size_t)t * HH + tid + 512] = __float2bfloat16(c2 * inv * g[tid + 512] + b[tid + 512]);
}

// ---------------------------------------------------------------------------
// Residual(bf16) + y(fp32) -> LayerNorm -> bf16 (in-place safe per-row)
// ---------------------------------------------------------------------------
__global__ __launch_bounds__(256) void add_ln(
    const __hip_bfloat16* __restrict__ resid, const float* __restrict__ y,
    const float* __restrict__ g, const float* __restrict__ b,
    __hip_bfloat16* __restrict__ hout)
{
    const int t = blockIdx.x;
    const int tid = threadIdx.x;
    __shared__ float x[HH];
    __shared__ float red[256];

    for (int j = tid; j < HH; j += 256)
        x[j] = __bfloat162float(resid[(size_t)t * HH + j]) + y[(size_t)t * HH + j];
    __syncthreads();

    float sum = x[tid] + x[tid + 256] + x[tid + 512];
    red[tid] = sum; __syncthreads();
    for (int s2 = 128; s2 > 0; s2 >>= 1) { if (tid < s2) red[tid] += red[tid + s2]; __syncthreads(); }
    const float mean = red[0] * (1.0f / HH);
    __syncthreads();

    const float c0 = x[tid] - mean, c1 = x[tid + 256] - mean, c2 = x[tid + 512] - mean;
    red[tid] = c0 * c0 + c1 * c1 + c2 * c2; __syncthreads();
    for (int s2 = 128; s2 > 0; s2 >>= 1) { if (tid < s2) red[tid] += red[tid + s2]; __syncthreads(); }
    const float inv = rsqrtf(red[0] * (1.0f / HH) + LN_EPS);

    hout[(size_t)t * HH + tid      ] = __float2bfloat16(c0 * inv * g[tid      ] + b[tid      ]);
    hout[(size_t)t * HH + tid + 256] = __float2bfloat16(c1 * inv * g[tid + 256] + b[tid + 256]);
    hout[(size_t)t * HH + tid + 512] = __float2bfloat16(c2 * inv * g[tid + 512] + b[tid + 512]);
}

// ---------------------------------------------------------------------------
// Flash attention v3: block = 256 threads = 128 queries x 2 threads/query.
// Thread pair (2q, 2q+1) splits d-dim in halves (32 regs each, no spills);
// full dot via __shfl_xor(.,1). qkv fp32 [T, 2304] (Q|K|V). ctx out bf16.
// K/V staged in LDS 64-key tiles, shared by all 4 waves.
// ---------------------------------------------------------------------------
__global__ __launch_bounds__(256) void attn_flash2(
    const float* __restrict__ qkv, __hip_bfloat16* __restrict__ ctx)
{
    const int qb  = blockIdx.x * 128;
    const int hh  = blockIdx.y;
    const int b   = blockIdx.z;
    const int tid = threadIdx.x;
    const int pair = tid >> 1;
    const int half = tid & 1;
    const int i = qb + pair;

    __shared__ float Ks[64][64];   // 16 KB
    __shared__ float Vs[64][64];   // 16 KB

    float qreg[32];
    {
        const float* qrow = qkv + (size_t)(b * SS + i) * QKVN + hh * DHH + half * 32;
        #pragma unroll
        for (int d4 = 0; d4 < 8; ++d4) {
            const float4 t4 = *(const float4*)(qrow + d4 * 4);
            qreg[d4 * 4 + 0] = t4.x; qreg[d4 * 4 + 1] = t4.y;
            qreg[d4 * 4 + 2] = t4.z; qreg[d4 * 4 + 3] = t4.w;
        }
    }
    float o[32];
    #pragma unroll
    for (int d = 0; d < 32; ++d) o[d] = 0.f;
    float m = -1e30f, lsum = 0.f;

    const int kmax = (qb + 128 > PROMPT) ? (qb + 128) : PROMPT;

    for (int j0 = 0; j0 < kmax; j0 += 64) {
        #pragma unroll
        for (int p = 0; p < 4; ++p) {
            const int seg = tid + p * 256;
            const int r = seg >> 4;
            const int c = (seg & 15) << 2;
            const float* gbase = qkv + (size_t)(b * SS + j0 + r) * QKVN + hh * DHH + c;
            *(float4*)&Ks[r][c] = *(const float4*)(gbase + HH);
            *(float4*)&Vs[r][c] = *(const float4*)(gbase + 2 * HH);
        }
        __syncthreads();

        const bool tfull = (j0 + 63 < PROMPT) || (j0 + 63 <= i);
        for (int jj = 0; jj < 64; ++jj) {
            const float* kp = &Ks[jj][half * 32];
            float s0 = 0.f, s1 = 0.f, s2 = 0.f, s3 = 0.f;
            #pragma unroll
            for (int d4 = 0; d4 < 8; ++d4) {
                const float4 k4 = *(const float4*)(kp + d4 * 4);
                s0 += qreg[d4 * 4 + 0] * k4.x; s1 += qreg[d4 * 4 + 1] * k4.y;
                s2 += qreg[d4 * 4 + 2] * k4.z; s3 += qreg[d4 * 4 + 3] * k4.w;
            }
            const float dh = (s0 + s1) + (s2 + s3);
            float s = (dh + __shfl_xor(dh, 1, 64)) * 0.125f;
            if (!tfull) {
                const int j = j0 + jj;
                if (!((j < PROMPT) || (j <= i))) s = -1e30f;
            }
            const float mnew = fmaxf(m, s);
            const float corr = __expf(m - mnew);
            const float p    = __expf(s - mnew);
            lsum = lsum * corr + p;
            const float* vp = &Vs[jj][half * 32];
            #pragma unroll
            for (int d4 = 0; d4 < 8; ++d4) {
                const float4 v4 = *(const float4*)(vp + d4 * 4);
                o[d4 * 4 + 0] = o[d4 * 4 + 0] * corr + p * v4.x;
                o[d4 * 4 + 1] = o[d4 * 4 + 1] * corr + p * v4.y;
                o[d4 * 4 + 2] = o[d4 * 4 + 2] * corr + p * v4.z;
                o[d4 * 4 + 3] = o[d4 * 4 + 3] * corr + p * v4.w;
            }
            m = mnew;
        }
        __syncthreads();
    }

    const float inv = 1.0f / lsum;
    __hip_bfloat16* crow = ctx + (size_t)(b * SS + i) * HH + hh * DHH + half * 32;
    #pragma unroll
    for (int d = 0; d < 32; ++d) crow[d] = __float2bfloat16(o[d] * inv);
}

// ---------------------------------------------------------------------------
// CE over one batch-chunk of logits (384 rows)
// ---------------------------------------------------------------------------
__global__ __launch_bounds__(256) void ce_kernel(
    const float* __restrict__ logits, const int* __restrict__ labels,
    int bidx, float* __restrict__ acc)
{
    const int r = blockIdx.x;
    const int t = bidx * SS + PROMPT + r;
    const float* row = logits + (size_t)r * VV;
    const int tid = threadIdx.x;
    __shared__ float red[256];

    float mx = -1e30f;
    for (int c = tid; c < VV; c += 256) mx = fmaxf(mx, row[c]);
    red[tid] = mx; __syncthreads();
    for (int s2 = 128; s2 > 0; s2 >>= 1) { if (tid < s2) red[tid] = fmaxf(red[tid], red[tid + s2]); __syncthreads(); }
    mx = red[0];
    __syncthreads();

    float se = 0.f;
    for (int c = tid; c < VV; c += 256) se += __expf(row[c] - mx);
    red[tid] = se; __syncthreads();
    for (int s2 = 128; s2 > 0; s2 >>= 1) { if (tid < s2) red[tid] += red[tid + s2]; __syncthreads(); }

    if (tid == 0) {
        const int lab = labels[t];
        if (lab >= 0) {
            const float nll = -(row[lab] - mx - logf(red[0]));
            atomicAdd(&acc[0], nll);
            atomicAdd(&acc[1], 1.0f);
        }
    }
}

__global__ void finalize_kernel(const float* __restrict__ acc, float* __restrict__ out)
{
    out[0] = (acc[1] > 0.f) ? acc[0] / acc[1] : 0.f;
}

// ---------------------------------------------------------------------------
extern "C" void kernel_launch(void* const* d_in, const int* in_sizes, int n_in,
                              void* d_out, int out_size, void* d_ws, size_t ws_size,
                              hipStream_t stream)
{
    const int*   input_ids = (const int*)  d_in[0];
    const int*   labels    = (const int*)  d_in[1];
    const float* word_emb  = (const float*)d_in[2];
    const float* pos_emb   = (const float*)d_in[3];
    const float* type_emb  = (const float*)d_in[4];
    const float* emb_ln_g  = (const float*)d_in[5];
    const float* emb_ln_b  = (const float*)d_in[6];
    const float* Wq = (const float*)d_in[7];   const float* bq = (const float*)d_in[8];
    const float* Wk = (const float*)d_in[9];   const float* bk = (const float*)d_in[10];
    const float* Wv = (const float*)d_in[11];  const float* bv = (const float*)d_in[12];
    const float* Wo = (const float*)d_in[13];  const float* bo = (const float*)d_in[14];
    const float* ln1_g = (const float*)d_in[15]; const float* ln1_b = (const float*)d_in[16];
    const float* W1 = (const float*)d_in[17];  const float* bf1 = (const float*)d_in[18];
    const float* W2 = (const float*)d_in[19];  const float* bf2 = (const float*)d_in[20];
    const float* ln2_g = (const float*)d_in[21]; const float* ln2_b = (const float*)d_in[22];
    const float* Wc = (const float*)d_in[23];  const float* bc = (const float*)d_in[24];

    // ---- workspace layout (fp32 first, then bf16) ----
    float* fws = (float*)d_ws;
    float* qkv  = fws;                        // 4096*2304 = 9,437,184 f
    float* lg   = qkv;                        // alias: 384*21128 = 8,113,152 f < qkv size
    float* tmp  = qkv + (size_t)TT * QKVN;    // 4096*768
    float* bqkv = tmp + (size_t)TT * HH;      // 12*2304
    float* acc  = bqkv + (size_t)LL * QKVN;   // 2 (+pad)

    __hip_bfloat16* bws = (__hip_bfloat16*)(acc + 8);
    __hip_bfloat16* h    = bws;                                   // 4096*768
    __hip_bfloat16* ctx  = h    + (size_t)TT * HH;                // 4096*768
    __hip_bfloat16* ff1  = ctx  + (size_t)TT * HH;                // 4096*3072
    __hip_bfloat16* qkvw = ff1  + (size_t)TT * FFF;               // 12*2304*768
    __hip_bfloat16* wot  = qkvw + (size_t)LL * QKVN * HH;         // 12*768*768
    __hip_bfloat16* w1t  = wot  + (size_t)LL * HH * HH;           // 12*3072*768
    __hip_bfloat16* w2t  = w1t  + (size_t)LL * FFF * HH;          // 12*768*3072
    __hip_bfloat16* wct  = w2t  + (size_t)LL * HH * FFF;          // 21248*768

    hipMemsetAsync(acc, 0, 2 * sizeof(float), stream);

    // ---- weight convert + transpose (bf16, K-contiguous) ----
    const dim3 tb(32, 8);
    transpose_cvt<<<dim3(24, 24, LL), tb, 0, stream>>>(Wq, qkvw, HH, HH,
        (long long)HH * HH, (long long)QKVN * HH, 0, HH);
    transpose_cvt<<<dim3(24, 24, LL), tb, 0, stream>>>(Wk, qkvw, HH, HH,
        (long long)HH * HH, (long long)QKVN * HH, HH, HH);
    transpose_cvt<<<dim3(24, 24, LL), tb, 0, stream>>>(Wv, qkvw, HH, HH,
        (long long)HH * HH, (long long)QKVN * HH, 2 * HH, HH);
    transpose_cvt<<<dim3(24, 24, LL), tb, 0, stream>>>(Wo, wot, HH, HH,
        (long long)HH * HH, (long long)HH * HH, 0, HH);
    transpose_cvt<<<dim3(96, 24, LL), tb, 0, stream>>>(W1, w1t, HH, FFF,
        (long long)HH * FFF, (long long)FFF * HH, 0, HH);
    transpose_cvt<<<dim3(24, 96, LL), tb, 0, stream>>>(W2, w2t, FFF, HH,
        (long long)FFF * HH, (long long)HH * FFF, 0, FFF);
    transpose_cvt<<<dim3(661, 24, 1), tb, 0, stream>>>(Wc, wct, HH, VV,
        0, 0, 0, HH);
    concat_bias<<<(LL * QKVN + 255) / 256, 256, 0, stream>>>(bq, bk, bv, bqkv);

    // ---- embeddings ----
    embed_ln<<<TT, 256, 0, stream>>>(input_ids, word_emb, pos_emb, type_emb,
                                     emb_ln_g, emb_ln_b, h);

    const dim3 gQKV(QKVN / 128, TT / 128);   // 18 x 32
    const dim3 gH(HH / 128, TT / 128);       // 6 x 32
    const dim3 gF(FFF / 128, TT / 128);      // 24 x 32
    const dim3 gAttn(SS / 128, NHH, BB);     // 4 x 12 x 8

    for (int l = 0; l < LL; ++l) {
        gemm_mfma<<<gQKV, 256, 0, stream>>>(h, qkvw + (size_t)l * QKVN * HH,
            bqkv + (size_t)l * QKVN, qkv, nullptr, TT, QKVN, HH, 0);

        attn_flash2<<<gAttn, 256, 0, stream>>>(qkv, ctx);

        gemm_mfma<<<gH, 256, 0, stream>>>(ctx, wot + (size_t)l * HH * HH,
            bo + (size_t)l * HH, tmp, nullptr, TT, HH, HH, 0);
        add_ln<<<TT, 256, 0, stream>>>(h, tmp, ln1_g + (size_t)l * HH, ln1_b + (size_t)l * HH, h);

        gemm_mfma<<<gF, 256, 0, stream>>>(h, w1t + (size_t)l * FFF * HH,
            bf1 + (size_t)l * FFF, nullptr, ff1, TT, FFF, HH, 1);
        gemm_mfma<<<gH, 256, 0, stream>>>(ff1, w2t + (size_t)l * HH * FFF,
            bf2 + (size_t)l * HH, tmp, nullptr, TT, HH, FFF, 0);
        add_ln<<<TT, 256, 0, stream>>>(h, tmp, ln2_g + (size_t)l * HH, ln2_b + (size_t)l * HH, h);
    }

    // ---- LM head + CE per batch (only s >= PROMPT rows) ----
    const int Mchunk = SS - PROMPT;              // 384
    const dim3 gV(VVP / 128, Mchunk / 128);      // 166 x 3
    for (int b = 0; b < BB; ++b) {
        const __hip_bfloat16* Arow = h + (size_t)(b * SS + PROMPT) * HH;
        gemm_mfma<<<gV, 256, 0, stream>>>(Arow, wct, bc, lg, nullptr, Mchunk, VV, HH, 0);
        ce_kernel<<<Mchunk, 256, 0, stream>>>(lg, labels, b, acc);
    }

    finalize_kernel<<<1, 1, 0, stream>>>(acc, (float*)d_out);
}